// Round 19
// baseline (24011.153 us; speedup 1.0000x reference)
//
#include <hip/hip_runtime.h>
#include <hip/hip_fp16.h>
#include <math.h>

#define BB    64
#define TT    2048
#define DIN   128
#define HH    512
#define NTHR  512     // 8 waves/WG -> 2 waves/SIMD by construction
#define BPG   4       // batches per group
#define NRNK  16      // WGs per group (each owns 32 cols)

typedef __attribute__((ext_vector_type(4))) unsigned int u32x4;
typedef __attribute__((ext_vector_type(8))) _Float16    f16x8;
typedef __attribute__((ext_vector_type(4))) float       f32x4;
typedef unsigned long long u64;

__device__ __forceinline__ float sigm(float v) { return 1.0f / (1.0f + expf(-v)); }

// ---- MALL (agent-scope) primitives — proven protocol (r4-r18) ----
__device__ __forceinline__ u32x4 ld16m(const void* p) {
  u32x4 v;
  asm volatile("global_load_dwordx4 %0, %1, off sc0 sc1" : "=v"(v) : "v"(p) : "memory");
  return v;
}
__device__ __forceinline__ void st8m(void* p, u64 v) {
  __hip_atomic_store((u64*)p, v, __ATOMIC_RELAXED, __HIP_MEMORY_SCOPE_AGENT);
}
__device__ __forceinline__ u64 ld8m(const void* p) {
  return __hip_atomic_load((const u64*)p, __ATOMIC_RELAXED, __HIP_MEMORY_SCOPE_AGENT);
}
__device__ __forceinline__ void gbar(unsigned* cnt, unsigned target, int* dead) {
  __syncthreads();
  if (threadIdx.x == 0 && *dead == 0) {
    asm volatile("s_waitcnt vmcnt(0)" ::: "memory");   // h-stores MALL-ack'd first
    __hip_atomic_fetch_add(cnt, 1u, __ATOMIC_RELAXED, __HIP_MEMORY_SCOPE_AGENT);
    long sp = 0;
    while (__hip_atomic_load(cnt, __ATOMIC_RELAXED, __HIP_MEMORY_SCOPE_AGENT) < target) {
      __builtin_amdgcn_s_sleep(1);
      if (++sp > (1L << 22)) { *dead = 1; break; }     // no-hang valve
    }
    asm volatile("" ::: "memory");
  }
  __syncthreads();
}

// ---- prep kernels -----------------------------------------------------------
__global__ __launch_bounds__(64, 1) void prep_flush() {
  extern __shared__ char dummy[];
  if (threadIdx.x == 0) { __threadfence(); dummy[0] = 0; }
  __syncthreads();
}
__global__ void prep_zero(unsigned* w) {
  const int total = (4*BB*HH*2 + 4096) / 4;   // h region + barrier words
  for (int i = blockIdx.x*blockDim.x + threadIdx.x; i < total; i += gridDim.x*blockDim.x)
    __hip_atomic_store(w + i, 0u, __ATOMIC_RELAXED, __HIP_MEMORY_SCOPE_AGENT);
}
__global__ void xcvt(const float* __restrict__ x, u64* __restrict__ xh) {
  const int N4 = BB*TT*DIN/4;
  const float4* x4 = reinterpret_cast<const float4*>(x);
  for (int i = blockIdx.x*blockDim.x + threadIdx.x; i < N4; i += gridDim.x*blockDim.x) {
    float4 v = x4[i];
    __half2 a = __floats2half2_rn(v.x, v.y);
    __half2 b = __floats2half2_rn(v.z, v.w);
    u64 u = ((u64)__builtin_bit_cast(unsigned, b) << 32) | (u64)__builtin_bit_cast(unsigned, a);
    __hip_atomic_store(&xh[i], u, __ATOMIC_RELAXED, __HIP_MEMORY_SCOPE_AGENT);
  }
}

// 256 WGs x 512 thr. WG = group (wg>>4) rank (wg&15): 4 batches x 32 h-cols,
// 8 waves x 4 cols. 47 weight frags in regs + 5 in LDS (r18-proven split).
__global__ __launch_bounds__(NTHR, 1) void lstm2_w8(
    const float* __restrict__ Wih0, const float* __restrict__ Whh0,
    const float* __restrict__ bih0, const float* __restrict__ bhh0,
    const float* __restrict__ Wih1, const float* __restrict__ Whh1,
    const float* __restrict__ bih1, const float* __restrict__ bhh1,
    const float* __restrict__ fcw,  const float* __restrict__ fcb,
    float* __restrict__ out, float* __restrict__ ws)
{
  constexpr int NUNITS = BPG * 144;          // 576: x 64 + h0 256 + h1 256
  constexpr int XB     = BPG * 16;           // 64
  constexpr int H1B    = XB + BPG * 64;      // 320
  constexpr int WOFF   = NUNITS * 16;        // 9216: LDS A-frag region (8 waves x 5KB)

  extern __shared__ char smbase[];
  __half* hout = reinterpret_cast<__half*>(smbase + WOFF + 8*5*1024);  // [2][4][32]
  int*    dead = reinterpret_cast<int*>(smbase + WOFF + 8*5*1024 + 512);

  const int tid  = threadIdx.x;
  const int wg   = blockIdx.x;
  const int lane = tid & 63;
  const int wv   = tid >> 6;        // 0..7

  const int grp  = wg >> 4;         // 16 batch groups
  const int r    = wg & 15;         // rank -> cols [32r, 32r+32)
  const int bg   = grp * BPG;
  const int c0   = 32*r + 4*wv;     // wave's 4 h-cols per layer

  __half* h0s = reinterpret_cast<__half*>(ws);     // 2 x [64][512] fp16
  __half* h1s = h0s + 2*BB*HH;
  unsigned* gcnt = reinterpret_cast<unsigned*>(reinterpret_cast<char*>(ws) + 262144) + grp*32;
  const __half* xh = reinterpret_cast<const __half*>(reinterpret_cast<char*>(ws) + 524288);

  // A-fragments, rt = jc*4 + gate (transpose-free epilogue, verified r10)
  const int rt   = lane & 15;
  const int gate = rt & 3;
  const int jc   = rt >> 2;
  const int kg   = lane >> 4;
  const int b15  = lane & 15;
  const int n0   = gate*HH + (c0 + jc);

  f16x8 af0[20];   // L0: K=640 = [x 0-127 | h0 128-639]
#pragma unroll
  for (int m = 0; m < 20; ++m) {
    int k0 = 32*m + 8*kg;
    const float* srcp = (k0 < DIN) ? (Wih0 + (size_t)n0*DIN + k0)
                                   : (Whh0 + (size_t)n0*HH + (k0 - DIN));
    float4 a = *reinterpret_cast<const float4*>(srcp);
    float4 b = *reinterpret_cast<const float4*>(srcp + 4);
    f16x8 fr;
    fr[0]=(_Float16)a.x; fr[1]=(_Float16)a.y; fr[2]=(_Float16)a.z; fr[3]=(_Float16)a.w;
    fr[4]=(_Float16)b.x; fr[5]=(_Float16)b.y; fr[6]=(_Float16)b.z; fr[7]=(_Float16)b.w;
    af0[m] = fr;
  }
  f16x8 af1[27];   // L1 m 0..26 in regs
#pragma unroll
  for (int m = 0; m < 27; ++m) {
    int k0 = 32*m + 8*kg;
    const float* srcp = (k0 < HH) ? (Wih1 + (size_t)n0*HH + k0)
                                  : (Whh1 + (size_t)n0*HH + (k0 - HH));
    float4 a = *reinterpret_cast<const float4*>(srcp);
    float4 b = *reinterpret_cast<const float4*>(srcp + 4);
    f16x8 fr;
    fr[0]=(_Float16)a.x; fr[1]=(_Float16)a.y; fr[2]=(_Float16)a.z; fr[3]=(_Float16)a.w;
    fr[4]=(_Float16)b.x; fr[5]=(_Float16)b.y; fr[6]=(_Float16)b.z; fr[7]=(_Float16)b.w;
    af1[m] = fr;
  }
  // L1 m 27..31 -> LDS (per-wave region; lane-contiguous = conflict-free)
#pragma unroll
  for (int m = 27; m < 32; ++m) {
    int k0 = 32*m + 8*kg;
    const float* srcp = Whh1 + (size_t)n0*HH + (k0 - HH);
    float4 a = *reinterpret_cast<const float4*>(srcp);
    float4 b = *reinterpret_cast<const float4*>(srcp + 4);
    f16x8 fr;
    fr[0]=(_Float16)a.x; fr[1]=(_Float16)a.y; fr[2]=(_Float16)a.z; fr[3]=(_Float16)a.w;
    fr[4]=(_Float16)b.x; fr[5]=(_Float16)b.y; fr[6]=(_Float16)b.z; fr[7]=(_Float16)b.w;
    *reinterpret_cast<f16x8*>(smbase + WOFF + ((wv*5 + (m-27))*64 + lane)*16) = fr;
  }

  const int cmy = c0 + kg;
  float bv0[4], bv1[4];
#pragma unroll
  for (int g = 0; g < 4; ++g) {
    bv0[g] = bih0[g*HH + cmy] + bhh0[g*HH + cmy];
    bv1[g] = bih1[g*HH + cmy] + bhh1[g*HH + cmy];
  }

  float cst0 = 0.f, cst1 = 0.f;
  const int beff = (b15 < BPG) ? b15 : (BPG - 1);
  const int bsw  = beff << 1;       // conflict-free swizzle (r18: conflicts -> 0)
  if (tid == 0) *dead = 0;
  __syncthreads();

  for (int st = 0; st <= TT; ++st) {
    const int tcur = (st < TT) ? st : (TT - 1);
    const __half* h0r = h0s + (size_t)(st & 1)*BB*HH;
    const __half* h1r = h1s + (size_t)(st & 1)*BB*HH;

    // ---- stage x + group h0 + h1 into LDS (576 units, 512 thr -> 2 iters) ----
    u32x4 stgL[2];
    int   physv[2];
#pragma unroll
    for (int ii = 0; ii < 2; ++ii) {
      int idx = tid + NTHR*ii;
      physv[ii] = -1;
      if (idx < NUNITS) {
        const __half* src; int phys;
        if (idx < XB)       { int b = idx>>4, u = idx&15;
          src = xh + (size_t)(bg+b)*TT*DIN + (size_t)tcur*DIN + u*8;
          phys = b*16 + (u ^ ((b<<1)&15)); }
        else if (idx < H1B) { int i2 = idx-XB,  b = i2>>6, u = i2&63;
          src = h0r + (size_t)(bg+b)*HH + u*8;
          phys = XB + b*64 + (u ^ (b<<1)); }
        else                { int i2 = idx-H1B, b = i2>>6, u = i2&63;
          src = h1r + (size_t)(bg+b)*HH + u*8;
          phys = H1B + b*64 + (u ^ (b<<1)); }
        physv[ii] = phys;
        stgL[ii] = ld16m(src);
      }
    }
    asm volatile("s_waitcnt vmcnt(0)" ::: "memory");
    __builtin_amdgcn_sched_barrier(0);
#pragma unroll
    for (int ii = 0; ii < 2; ++ii)
      if (physv[ii] >= 0)
        *reinterpret_cast<u32x4*>(smbase + physv[ii]*16) = stgL[ii];
    __syncthreads();

    // ---- MFMA: L0 (20) + L1 (32; last 5 A-frags from LDS), 2-way acc split ----
    f32x4 a0a = {0.f,0.f,0.f,0.f}, a0b = a0a, a1a = a0a, a1b = a0a;
#pragma unroll
    for (int m = 0; m < 20; ++m) {
      int phys = (m < 4) ? (beff*16 + ((4*m + kg) ^ (bsw & 15)))
                         : (XB + beff*64 + ((4*(m-4) + kg) ^ bsw));
      f16x8 bf = *reinterpret_cast<const f16x8*>(smbase + phys*16);
      if (m & 1) a0b = __builtin_amdgcn_mfma_f32_16x16x32_f16(af0[m], bf, a0b, 0, 0, 0);
      else       a0a = __builtin_amdgcn_mfma_f32_16x16x32_f16(af0[m], bf, a0a, 0, 0, 0);
    }
#pragma unroll
    for (int m = 0; m < 27; ++m) {
      int phys = (m < 16) ? (XB + beff*64 + ((4*m + kg) ^ bsw))
                          : (H1B + beff*64 + ((4*(m-16) + kg) ^ bsw));
      f16x8 bf = *reinterpret_cast<const f16x8*>(smbase + phys*16);
      if (m & 1) a1b = __builtin_amdgcn_mfma_f32_16x16x32_f16(af1[m], bf, a1b, 0, 0, 0);
      else       a1a = __builtin_amdgcn_mfma_f32_16x16x32_f16(af1[m], bf, a1a, 0, 0, 0);
    }
#pragma unroll
    for (int m = 27; m < 32; ++m) {
      int woff = WOFF + ((wv*5 + (m-27))*64 + lane)*16;
      asm volatile("" : "+v"(woff));   // keep A-read per-step, block hoist
      f16x8 aw = *reinterpret_cast<const f16x8*>(smbase + woff);
      int phys = H1B + beff*64 + ((4*(m-16) + kg) ^ bsw);
      f16x8 bf = *reinterpret_cast<const f16x8*>(smbase + phys*16);
      if (m & 1) a1b = __builtin_amdgcn_mfma_f32_16x16x32_f16(aw, bf, a1b, 0, 0, 0);
      else       a1a = __builtin_amdgcn_mfma_f32_16x16x32_f16(aw, bf, a1a, 0, 0, 0);
    }
    f32x4 a0 = a0a + a0b;
    f32x4 a1 = a1a + a1b;

    // ---- gates directly from acc (a[j] = gate j of (col cmy, batch b15)) ----
    if (st < TT) {
      float gi = sigm (a0[0] + bv0[0]);
      float gf = sigm (a0[1] + bv0[1]);
      float gg = tanhf(a0[2] + bv0[2]);
      float go = sigm (a0[3] + bv0[3]);
      cst0 = gf*cst0 + gi*gg;
      float hn = go * tanhf(cst0);
      if (b15 < BPG) hout[0*(BPG*32) + b15*32 + 4*wv + kg] = __float2half(hn);
    }
    if (st >= 1) {
      float gi = sigm (a1[0] + bv1[0]);
      float gf = sigm (a1[1] + bv1[1]);
      float gg = tanhf(a1[2] + bv1[2]);
      float go = sigm (a1[3] + bv1[3]);
      cst1 = gf*cst1 + gi*gg;
      float hn = go * tanhf(cst1);
      if (b15 < BPG) hout[1*(BPG*32) + b15*32 + 4*wv + kg] = __float2half(hn);
    }
    __syncthreads();

    // ---- pack-store h (2 layers x 4 batches x 8 parts of 4 cols, 8B each) ----
    if (tid < 64) {
      int layer = tid >> 5, q = tid & 31, b = q >> 3, part = q & 7;
      bool do_st = (layer == 0) ? (st < TT) : (st >= 1);
      if (do_st) {
        u64 v = *reinterpret_cast<u64*>(hout + layer*(BPG*32) + b*32 + part*4);
        __half* base = (layer ? h1s : h0s) + (size_t)((st + 1) & 1)*BB*HH;
        st8m(base + (size_t)(bg+b)*HH + 32*r + part*4, v);
      }
    }
    gbar(gcnt, (unsigned)NRNK*(unsigned)(st + 1), dead);
  }

  // ---- FC on final h1 (parity 1): 32 outputs/WG (4 b x 8 cols), 16 thr each ----
  {
    const __half* h1f = h1s + (size_t)BB*HH;
    int oi = tid >> 4, kp = tid & 15;     // oi 0..31, kp 0..15
    int b  = oi >> 3, cc = oi & 7;
    int ocol = 8*r + cc;
    const u64* h8 = reinterpret_cast<const u64*>(h1f + (size_t)(bg+b)*HH) + kp*8;
    const float* wrow = fcw + (size_t)ocol*HH + kp*32;
    float p = 0.f;
#pragma unroll
    for (int kk = 0; kk < 8; ++kk) {
      u64 v = ld8m(h8 + kk);
      __half2 hlo = __builtin_bit_cast(__half2, (unsigned)(v & 0xffffffffull));
      __half2 hhi = __builtin_bit_cast(__half2, (unsigned)(v >> 32));
      float2 flo = __half22float2(hlo), fhi = __half22float2(hhi);
      float4 w = *reinterpret_cast<const float4*>(wrow + kk*4);
      p += flo.x*w.x + flo.y*w.y + fhi.x*w.z + fhi.y*w.w;
    }
    p += __shfl_xor(p, 1);
    p += __shfl_xor(p, 2);
    p += __shfl_xor(p, 4);
    p += __shfl_xor(p, 8);
    if (kp == 0) out[(size_t)(bg+b)*128 + ocol] = p + fcb[ocol];
  }
}

__global__ void sentinel_fail(float* out, float v) { out[threadIdx.x] = v; }

extern "C" void kernel_launch(void* const* d_in, const int* in_sizes, int n_in,
                              void* d_out, int out_size, void* d_ws, size_t ws_size,
                              hipStream_t stream) {
  const float* x    = (const float*)d_in[0];
  const float* Wih0 = (const float*)d_in[1];
  const float* Whh0 = (const float*)d_in[2];
  const float* bih0 = (const float*)d_in[3];
  const float* bhh0 = (const float*)d_in[4];
  const float* Wih1 = (const float*)d_in[5];
  const float* Whh1 = (const float*)d_in[6];
  const float* bih1 = (const float*)d_in[7];
  const float* bhh1 = (const float*)d_in[8];
  const float* fcw  = (const float*)d_in[9];
  const float* fcb  = (const float*)d_in[10];
  float* out = (float*)d_out;
  float* ws  = (float*)d_ws;
  (void)in_sizes; (void)n_in; (void)out_size;

  const size_t need = 524288 + (size_t)BB*TT*DIN*2;
  if (ws_size < need) {
    sentinel_fail<<<1, 128, 0, stream>>>(out, 2.0e6f);
    return;
  }

  const int flush_smem = 108*1024;
  // staging 9216 + LDS weights 40960 + hout/dead 1024 -> ~50KB (1 WG/CU)
  const int smem = 51*1024;
  hipFuncSetAttribute(reinterpret_cast<const void*>(&lstm2_w8),
                      hipFuncAttributeMaxDynamicSharedMemorySize, smem);
  hipFuncSetAttribute(reinterpret_cast<const void*>(&prep_flush),
                      hipFuncAttributeMaxDynamicSharedMemorySize, flush_smem);

  (void)hipGetLastError();
  prep_flush<<<dim3(256), dim3(64), flush_smem, stream>>>();
  xcvt<<<dim3(2048), dim3(256), 0, stream>>>(
      x, reinterpret_cast<u64*>(reinterpret_cast<char*>(d_ws) + 524288));
  prep_zero<<<dim3(256), dim3(256), 0, stream>>>((unsigned*)d_ws);
  // 512-thread WG forces 8 waves on 4 SIMDs = 2 waves/SIMD; compiler must fit
  // each wave in <=256 total (arch+AGPR) regs or the kernel cannot launch.
  lstm2_w8<<<dim3(256), dim3(NTHR), smem, stream>>>(
      Wih0, Whh0, bih0, bhh0, Wih1, Whh1, bih1, bhh1, fcw, fcb, out, ws);
  hipError_t e = hipGetLastError();
  if (e != hipSuccess) {
    sentinel_fail<<<1, 128, 0, stream>>>(out, 1.0e6f);
  }
}

// Round 21
// 8454.823 us; speedup vs baseline: 2.8399x; 2.8399x over previous
//
#include <hip/hip_runtime.h>
#include <hip/hip_fp16.h>
#include <math.h>

#define BB    64
#define TT    2048
#define DIN   128
#define HH    512
#define NWG   256
#define NTHR  256
#define NUNITS 1152  // staged 16B units: x 128 + h0 512 + h1 512

typedef __attribute__((ext_vector_type(4))) unsigned int u32x4;
typedef __attribute__((ext_vector_type(8))) _Float16    f16x8;
typedef __attribute__((ext_vector_type(4))) float       f32x4;
typedef unsigned long long u64;

__device__ __forceinline__ float sigm(float v) { return 1.0f / (1.0f + expf(-v)); }

// ---- MALL (agent-scope) primitives — the ONLY protocol with verified passes ----
__device__ __forceinline__ u32x4 ld16m(const void* p) {
  u32x4 v;
  asm volatile("global_load_dwordx4 %0, %1, off sc0 sc1" : "=v"(v) : "v"(p) : "memory");
  return v;
}
__device__ __forceinline__ void st8m(void* p, u64 v) {
  __hip_atomic_store((u64*)p, v, __ATOMIC_RELAXED, __HIP_MEMORY_SCOPE_AGENT);
}
__device__ __forceinline__ u64 ld8m(const void* p) {
  return __hip_atomic_load((const u64*)p, __ATOMIC_RELAXED, __HIP_MEMORY_SCOPE_AGENT);
}

// ---- prep kernels -----------------------------------------------------------
__global__ __launch_bounds__(64, 1) void prep_flush() {
  extern __shared__ char dummy[];
  if (threadIdx.x == 0) { __threadfence(); dummy[0] = 0; }
  __syncthreads();
}
__global__ void prep_zero(unsigned* w) {
  const int total = (4*BB*HH*2 + 8192) / 4;   // h region + flag lines
  for (int i = blockIdx.x*blockDim.x + threadIdx.x; i < total; i += gridDim.x*blockDim.x)
    __hip_atomic_store(w + i, 0u, __ATOMIC_RELAXED, __HIP_MEMORY_SCOPE_AGENT);
}
__global__ void xcvt(const float* __restrict__ x, u64* __restrict__ xh) {
  const int N4 = BB*TT*DIN/4;
  const float4* x4 = reinterpret_cast<const float4*>(x);
  for (int i = blockIdx.x*blockDim.x + threadIdx.x; i < N4; i += gridDim.x*blockDim.x) {
    float4 v = x4[i];
    __half2 a = __floats2half2_rn(v.x, v.y);
    __half2 b = __floats2half2_rn(v.z, v.w);
    u64 u = ((u64)__builtin_bit_cast(unsigned, b) << 32) | (u64)__builtin_bit_cast(unsigned, a);
    __hip_atomic_store(&xh[i], u, __ATOMIC_RELAXED, __HIP_MEMORY_SCOPE_AGENT);
  }
}

// r10 structure (proven): 256 WGs = 8 groups x 32 ranks, BPG=8, MALL exchange.
// New vs r10: (a) conflict-free swizzle bsw=beff<<1 (r18: conflicts->0),
// (b) flag-based seq barrier (agent atomics; no counter RMW serialization).
__global__ __launch_bounds__(NTHR, 1) void lstm2_fb(
    const float* __restrict__ Wih0, const float* __restrict__ Whh0,
    const float* __restrict__ bih0, const float* __restrict__ bhh0,
    const float* __restrict__ Wih1, const float* __restrict__ Whh1,
    const float* __restrict__ bih1, const float* __restrict__ bhh1,
    const float* __restrict__ fcw,  const float* __restrict__ fcb,
    float* __restrict__ out, float* __restrict__ ws)
{
  extern __shared__ char smbase[];
  __half* hout = reinterpret_cast<__half*>(smbase + 18432);   // [2][8][16]
  int*    dead = reinterpret_cast<int*>(smbase + 18944);

  const int tid  = threadIdx.x;
  const int wg   = blockIdx.x;
  const int lane = tid & 63;
  const int wv   = tid >> 6;

  const int grp  = wg >> 5;        // batch group (8 rows)
  const int r    = wg & 31;        // rank -> h-cols [16r,16r+16)
  const int bg8  = grp * 8;
  const int c0   = 16*r + 4*wv;

  __half* h0s = reinterpret_cast<__half*>(ws);     // 2 x [64][512] fp16
  __half* h1s = h0s + 2*BB*HH;
  unsigned* flg = reinterpret_cast<unsigned*>((char*)ws + 262144) + grp*32;  // 128B line/group
  const __half* xh = reinterpret_cast<const __half*>((char*)ws + 524288);

  // A-fragments, rt = jc*4 + gate (transpose-free epilogue, verified r10)
  const int rt   = lane & 15;
  const int gate = rt & 3;
  const int jc   = rt >> 2;
  const int kg   = lane >> 4;
  const int b15  = lane & 15;
  const int n0   = gate*HH + (c0 + jc);

  f16x8 af0[20];   // L0: K=640 = [x 0-127 | h0 128-639]
#pragma unroll
  for (int m = 0; m < 20; ++m) {
    int k0 = 32*m + 8*kg;
    const float* srcp = (k0 < DIN) ? (Wih0 + (size_t)n0*DIN + k0)
                                   : (Whh0 + (size_t)n0*HH + (k0 - DIN));
    float4 a = *reinterpret_cast<const float4*>(srcp);
    float4 b = *reinterpret_cast<const float4*>(srcp + 4);
    f16x8 fr;
    fr[0]=(_Float16)a.x; fr[1]=(_Float16)a.y; fr[2]=(_Float16)a.z; fr[3]=(_Float16)a.w;
    fr[4]=(_Float16)b.x; fr[5]=(_Float16)b.y; fr[6]=(_Float16)b.z; fr[7]=(_Float16)b.w;
    af0[m] = fr;
  }
  f16x8 af1[32];   // L1: K=1024 = [h0 (W_ih1) | h1 (W_hh1)]
#pragma unroll
  for (int m = 0; m < 32; ++m) {
    int k0 = 32*m + 8*kg;
    const float* srcp = (k0 < HH) ? (Wih1 + (size_t)n0*HH + k0)
                                  : (Whh1 + (size_t)n0*HH + (k0 - HH));
    float4 a = *reinterpret_cast<const float4*>(srcp);
    float4 b = *reinterpret_cast<const float4*>(srcp + 4);
    f16x8 fr;
    fr[0]=(_Float16)a.x; fr[1]=(_Float16)a.y; fr[2]=(_Float16)a.z; fr[3]=(_Float16)a.w;
    fr[4]=(_Float16)b.x; fr[5]=(_Float16)b.y; fr[6]=(_Float16)b.z; fr[7]=(_Float16)b.w;
    af1[m] = fr;
  }

  const int cmy = c0 + kg;
  float bv0[4], bv1[4];
#pragma unroll
  for (int g = 0; g < 4; ++g) {
    bv0[g] = bih0[g*HH + cmy] + bhh0[g*HH + cmy];
    bv1[g] = bih1[g*HH + cmy] + bhh1[g*HH + cmy];
  }

  float cst0 = 0.f, cst1 = 0.f;
  const int beff = (b15 < 8) ? b15 : 7;
  const int bsw  = beff << 1;      // conflict-free swizzle: (u^2b) mod 8 only 2-way
  if (tid == 0) *dead = 0;
  __syncthreads();

  for (int st = 0; st <= TT; ++st) {
    const int tcur = (st < TT) ? st : (TT - 1);
    const __half* h0r = h0s + (size_t)(st & 1)*BB*HH;
    const __half* h1r = h1s + (size_t)(st & 1)*BB*HH;

    // ---- stage x-slice + group h0 + h1 into LDS (18 KB, swizzled) ----
    u32x4 stgL[5];
    int   physv[5];
#pragma unroll
    for (int ii = 0; ii < 5; ++ii) {
      int idx = tid + NTHR*ii;
      physv[ii] = -1;
      if (idx < NUNITS) {
        const __half* src; int phys;
        if (idx < 128)      { int b = idx>>4, u = idx&15;
          src = xh + (size_t)(bg8+b)*TT*DIN + (size_t)tcur*DIN + u*8;
          phys = b*16 + (u ^ ((b<<1)&15)); }
        else if (idx < 640) { int i2 = idx-128, b = i2>>6, u = i2&63;
          src = h0r + (size_t)(bg8+b)*HH + u*8;
          phys = 128 + b*64 + (u ^ (b<<1)); }
        else                { int i2 = idx-640, b = i2>>6, u = i2&63;
          src = h1r + (size_t)(bg8+b)*HH + u*8;
          phys = 640 + b*64 + (u ^ (b<<1)); }
        physv[ii] = phys;
        stgL[ii] = ld16m(src);
      }
    }
    asm volatile("s_waitcnt vmcnt(0)" ::: "memory");
    __builtin_amdgcn_sched_barrier(0);
#pragma unroll
    for (int ii = 0; ii < 5; ++ii)
      if (physv[ii] >= 0)
        *reinterpret_cast<u32x4*>(smbase + physv[ii]*16) = stgL[ii];
    __syncthreads();

    // ---- MFMA: L0 (20) + L1 (32), 2-way acc split ----
    f32x4 a0a = {0.f,0.f,0.f,0.f}, a0b = a0a, a1a = a0a, a1b = a0a;
#pragma unroll
    for (int m = 0; m < 20; ++m) {
      int phys = (m < 4) ? (beff*16 + ((4*m + kg) ^ (bsw & 15)))
                         : (128 + beff*64 + ((4*(m-4) + kg) ^ bsw));
      f16x8 bf = *reinterpret_cast<const f16x8*>(smbase + phys*16);
      if (m & 1) a0b = __builtin_amdgcn_mfma_f32_16x16x32_f16(af0[m], bf, a0b, 0, 0, 0);
      else       a0a = __builtin_amdgcn_mfma_f32_16x16x32_f16(af0[m], bf, a0a, 0, 0, 0);
    }
#pragma unroll
    for (int m = 0; m < 32; ++m) {
      int phys = (m < 16) ? (128 + beff*64 + ((4*m + kg) ^ bsw))
                          : (640 + beff*64 + ((4*(m-16) + kg) ^ bsw));
      f16x8 bf = *reinterpret_cast<const f16x8*>(smbase + phys*16);
      if (m & 1) a1b = __builtin_amdgcn_mfma_f32_16x16x32_f16(af1[m], bf, a1b, 0, 0, 0);
      else       a1a = __builtin_amdgcn_mfma_f32_16x16x32_f16(af1[m], bf, a1a, 0, 0, 0);
    }
    f32x4 a0 = a0a + a0b;
    f32x4 a1 = a1a + a1b;

    // ---- gates directly from acc (a[j] = gate j of (col cmy, batch b15)) ----
    if (st < TT) {
      float gi = sigm (a0[0] + bv0[0]);
      float gf = sigm (a0[1] + bv0[1]);
      float gg = tanhf(a0[2] + bv0[2]);
      float go = sigm (a0[3] + bv0[3]);
      cst0 = gf*cst0 + gi*gg;
      float hn = go * tanhf(cst0);
      if (b15 < 8) hout[(0*8 + b15)*16 + 4*wv + kg] = __float2half(hn);
    }
    if (st >= 1) {
      float gi = sigm (a1[0] + bv1[0]);
      float gf = sigm (a1[1] + bv1[1]);
      float gg = tanhf(a1[2] + bv1[2]);
      float go = sigm (a1[3] + bv1[3]);
      cst1 = gf*cst1 + gi*gg;
      float hn = go * tanhf(cst1);
      if (b15 < 8) hout[(1*8 + b15)*16 + 4*wv + kg] = __float2half(hn);
    }
    __syncthreads();

    // ---- pack-store h (wave 0: 64 x 8B agent-scope stores to MALL) ----
    if (tid < 64) {
      int layer = tid >> 5, q = tid & 31, b = q >> 2, part = q & 3;
      bool do_st = (layer == 0) ? (st < TT) : (st >= 1);
      if (do_st) {
        u64 v = *reinterpret_cast<u64*>(hout + (layer*8 + b)*16 + part*4);
        __half* base = (layer ? h1s : h0s) + (size_t)((st + 1) & 1)*BB*HH;
        st8m(base + (size_t)(bg8+b)*HH + 16*r + part*4, v);
      }
    }

    // ---- flag-based group barrier (monotonic seq; agent atomics only) ----
    __syncthreads();                 // all waves done; wave0's h-stores issued
    if (wv == 0 && *dead == 0) {
      asm volatile("s_waitcnt vmcnt(0)" ::: "memory");   // h-stores MALL-ack'd
      if (lane == 0)
        __hip_atomic_store(flg + r, (unsigned)(st + 1),
                           __ATOMIC_RELAXED, __HIP_MEMORY_SCOPE_AGENT);
      long sp = 0;
      for (;;) {
        unsigned f = 0u;
        if (lane < 32)
          f = __hip_atomic_load(flg + lane, __ATOMIC_RELAXED, __HIP_MEMORY_SCOPE_AGENT);
        bool ok = (lane < 32) ? (f >= (unsigned)(st + 1)) : true;
        if (__all(ok)) break;
        __builtin_amdgcn_s_sleep(1);
        if (++sp > (1L << 22)) { if (lane == 0) *dead = 1; break; }  // no-hang valve
      }
      asm volatile("" ::: "memory");
    }
    __syncthreads();
  }

  // ---- FC on final h1 (parity 1) ----
  {
    const __half* h1f = h1s + (size_t)BB*HH;
    int oi = tid >> 3, kp = tid & 7;
    int b  = oi >> 2, cc = oi & 3;
    int ocol = 4*r + cc;
    const u64* h8 = reinterpret_cast<const u64*>(h1f + (size_t)(bg8+b)*HH) + kp*16;
    const float* wrow = fcw + (size_t)ocol*HH + kp*64;
    float p = 0.f;
#pragma unroll
    for (int kk = 0; kk < 16; ++kk) {
      u64 v = ld8m(h8 + kk);
      __half2 hlo = __builtin_bit_cast(__half2, (unsigned)(v & 0xffffffffull));
      __half2 hhi = __builtin_bit_cast(__half2, (unsigned)(v >> 32));
      float2 flo = __half22float2(hlo), fhi = __half22float2(hhi);
      float4 w = *reinterpret_cast<const float4*>(wrow + kk*4);
      p += flo.x*w.x + flo.y*w.y + fhi.x*w.z + fhi.y*w.w;
    }
    p += __shfl_xor(p, 1);
    p += __shfl_xor(p, 2);
    p += __shfl_xor(p, 4);
    if (kp == 0) out[(size_t)(bg8+b)*128 + ocol] = p + fcb[ocol];
  }
}

__global__ void sentinel_fail(float* out, float v) { out[threadIdx.x] = v; }

extern "C" void kernel_launch(void* const* d_in, const int* in_sizes, int n_in,
                              void* d_out, int out_size, void* d_ws, size_t ws_size,
                              hipStream_t stream) {
  const float* x    = (const float*)d_in[0];
  const float* Wih0 = (const float*)d_in[1];
  const float* Whh0 = (const float*)d_in[2];
  const float* bih0 = (const float*)d_in[3];
  const float* bhh0 = (const float*)d_in[4];
  const float* Wih1 = (const float*)d_in[5];
  const float* Whh1 = (const float*)d_in[6];
  const float* bih1 = (const float*)d_in[7];
  const float* bhh1 = (const float*)d_in[8];
  const float* fcw  = (const float*)d_in[9];
  const float* fcb  = (const float*)d_in[10];
  float* out = (float*)d_out;
  float* ws  = (float*)d_ws;
  (void)in_sizes; (void)n_in; (void)out_size;

  const size_t need = 524288 + (size_t)BB*TT*DIN*2;
  if (ws_size < need) {
    sentinel_fail<<<1, 128, 0, stream>>>(out, 2.0e6f);
    return;
  }

  const int smem_bytes = 108*1024;   // forces 1 WG/CU (occupancy axis closed)
  hipFuncSetAttribute(reinterpret_cast<const void*>(&lstm2_fb),
                      hipFuncAttributeMaxDynamicSharedMemorySize, smem_bytes);
  hipFuncSetAttribute(reinterpret_cast<const void*>(&prep_flush),
                      hipFuncAttributeMaxDynamicSharedMemorySize, smem_bytes);

  (void)hipGetLastError();
  prep_flush<<<dim3(NWG), dim3(64), smem_bytes, stream>>>();
  xcvt<<<dim3(2048), dim3(NTHR), 0, stream>>>(
      x, reinterpret_cast<u64*>(reinterpret_cast<char*>(d_ws) + 524288));
  prep_zero<<<dim3(NWG), dim3(NTHR), 0, stream>>>((unsigned*)d_ws);
  lstm2_fb<<<dim3(NWG), dim3(NTHR), smem_bytes, stream>>>(
      Wih0, Whh0, bih0, bhh0, Wih1, Whh1, bih1, bhh1, fcw, fcb, out, ws);
  hipError_t e = hipGetLastError();
  if (e != hipSuccess) {
    sentinel_fail<<<1, 128, 0, stream>>>(out, 1.0e6f);
  }
}

// Round 22
// 7709.606 us; speedup vs baseline: 3.1144x; 1.0967x over previous
//
#include <hip/hip_runtime.h>
#include <hip/hip_fp16.h>
#include <math.h>

#define BB    64
#define TT    2048
#define DIN   128
#define HH    512
#define NWG   256
#define NTHR  256

typedef __attribute__((ext_vector_type(4))) unsigned int u32x4;
typedef __attribute__((ext_vector_type(8))) _Float16    f16x8;
typedef __attribute__((ext_vector_type(4))) float       f32x4;
typedef unsigned long long u64;

__device__ __forceinline__ float sigm(float v) { return 1.0f / (1.0f + expf(-v)); }

// ---- MALL (agent-scope) primitives — the only protocol with verified passes ----
__device__ __forceinline__ u32x4 ld16m(const void* p) {
  u32x4 v;
  asm volatile("global_load_dwordx4 %0, %1, off sc0 sc1" : "=v"(v) : "v"(p) : "memory");
  return v;
}
__device__ __forceinline__ void st8m(void* p, u64 v) {
  __hip_atomic_store((u64*)p, v, __ATOMIC_RELAXED, __HIP_MEMORY_SCOPE_AGENT);
}
__device__ __forceinline__ u64 ld8m(const void* p) {
  return __hip_atomic_load((const u64*)p, __ATOMIC_RELAXED, __HIP_MEMORY_SCOPE_AGENT);
}
// flag poll (r21-proven): lanes<32 read the group's 32 flags, __all ballot
__device__ __forceinline__ void fpoll(unsigned* flags, unsigned target, int lane, int* dead) {
  if (*dead) return;
  long sp = 0;
  for (;;) {
    unsigned f = 0u;
    if (lane < 32)
      f = __hip_atomic_load(flags + lane, __ATOMIC_RELAXED, __HIP_MEMORY_SCOPE_AGENT);
    bool ok = (lane < 32) ? (f >= target) : true;
    if (__all(ok)) break;
    __builtin_amdgcn_s_sleep(1);
    if (++sp > (1L << 22)) { if (lane == 0) *dead = 1; break; }   // no-hang valve
  }
  asm volatile("" ::: "memory");
}

// ---- prep kernels -----------------------------------------------------------
__global__ __launch_bounds__(64, 1) void prep_flush() {
  extern __shared__ char dummy[];
  if (threadIdx.x == 0) { __threadfence(); dummy[0] = 0; }
  __syncthreads();
}
__global__ void prep_zero(unsigned* w) {
  const int total = (4*BB*HH*2 + 16384) / 4;   // h region + flagA/flagB lines
  for (int i = blockIdx.x*blockDim.x + threadIdx.x; i < total; i += gridDim.x*blockDim.x)
    __hip_atomic_store(w + i, 0u, __ATOMIC_RELAXED, __HIP_MEMORY_SCOPE_AGENT);
}
__global__ void xcvt(const float* __restrict__ x, u64* __restrict__ xh) {
  const int N4 = BB*TT*DIN/4;
  const float4* x4 = reinterpret_cast<const float4*>(x);
  for (int i = blockIdx.x*blockDim.x + threadIdx.x; i < N4; i += gridDim.x*blockDim.x) {
    float4 v = x4[i];
    __half2 a = __floats2half2_rn(v.x, v.y);
    __half2 b = __floats2half2_rn(v.z, v.w);
    u64 u = ((u64)__builtin_bit_cast(unsigned, b) << 32) | (u64)__builtin_bit_cast(unsigned, a);
    __hip_atomic_store(&xh[i], u, __ATOMIC_RELAXED, __HIP_MEMORY_SCOPE_AGENT);
  }
}

// Split-flag two-phase pipeline on the r21 base.
// Phase A: pollA(st) -> load x+h0 -> [vmcnt covers prev h1' acks] -> flagB=st
//          -> L0(20)+L1A(16) MFMA -> gates L0 -> issue h0' stores.
// Phase B: pollB(st) -> load h1 -> [vmcnt covers h0' acks] -> flagA=st+1
//          -> L1B(16) MFMA -> gates L1 -> issue h1' stores (ack next step).
__global__ __launch_bounds__(NTHR, 1) void lstm2_sp(
    const float* __restrict__ Wih0, const float* __restrict__ Whh0,
    const float* __restrict__ bih0, const float* __restrict__ bhh0,
    const float* __restrict__ Wih1, const float* __restrict__ Whh1,
    const float* __restrict__ bih1, const float* __restrict__ bhh1,
    const float* __restrict__ fcw,  const float* __restrict__ fcb,
    float* __restrict__ out, float* __restrict__ ws)
{
  extern __shared__ char smbase[];
  __half* hout = reinterpret_cast<__half*>(smbase + 18432);   // [2][8][16]
  int*    dead = reinterpret_cast<int*>(smbase + 18944);

  const int tid  = threadIdx.x;
  const int wg   = blockIdx.x;
  const int lane = tid & 63;
  const int wv   = tid >> 6;

  const int grp  = wg >> 5;        // batch group (8 rows)
  const int r    = wg & 31;        // rank -> h-cols [16r,16r+16)
  const int bg8  = grp * 8;
  const int c0   = 16*r + 4*wv;

  __half* h0s = reinterpret_cast<__half*>(ws);     // 2 x [64][512] fp16
  __half* h1s = h0s + 2*BB*HH;
  unsigned* flgA = reinterpret_cast<unsigned*>((char*)ws + 262144) + grp*32;
  unsigned* flgB = reinterpret_cast<unsigned*>((char*)ws + 266240) + grp*32;
  const __half* xh = reinterpret_cast<const __half*>((char*)ws + 524288);

  // A-fragments, rt = jc*4 + gate (transpose-free epilogue, verified r10)
  const int rt   = lane & 15;
  const int gate = rt & 3;
  const int jc   = rt >> 2;
  const int kg   = lane >> 4;
  const int b15  = lane & 15;
  const int n0   = gate*HH + (c0 + jc);

  f16x8 af0[20];   // L0: K=640 = [x 0-127 | h0 128-639]
#pragma unroll
  for (int m = 0; m < 20; ++m) {
    int k0 = 32*m + 8*kg;
    const float* srcp = (k0 < DIN) ? (Wih0 + (size_t)n0*DIN + k0)
                                   : (Whh0 + (size_t)n0*HH + (k0 - DIN));
    float4 a = *reinterpret_cast<const float4*>(srcp);
    float4 b = *reinterpret_cast<const float4*>(srcp + 4);
    f16x8 fr;
    fr[0]=(_Float16)a.x; fr[1]=(_Float16)a.y; fr[2]=(_Float16)a.z; fr[3]=(_Float16)a.w;
    fr[4]=(_Float16)b.x; fr[5]=(_Float16)b.y; fr[6]=(_Float16)b.z; fr[7]=(_Float16)b.w;
    af0[m] = fr;
  }
  f16x8 af1[32];   // L1: K=1024 = [h0 (W_ih1) m0-15 | h1 (W_hh1) m16-31]
#pragma unroll
  for (int m = 0; m < 32; ++m) {
    int k0 = 32*m + 8*kg;
    const float* srcp = (k0 < HH) ? (Wih1 + (size_t)n0*HH + k0)
                                  : (Whh1 + (size_t)n0*HH + (k0 - HH));
    float4 a = *reinterpret_cast<const float4*>(srcp);
    float4 b = *reinterpret_cast<const float4*>(srcp + 4);
    f16x8 fr;
    fr[0]=(_Float16)a.x; fr[1]=(_Float16)a.y; fr[2]=(_Float16)a.z; fr[3]=(_Float16)a.w;
    fr[4]=(_Float16)b.x; fr[5]=(_Float16)b.y; fr[6]=(_Float16)b.z; fr[7]=(_Float16)b.w;
    af1[m] = fr;
  }

  const int cmy = c0 + kg;
  float bv0[4], bv1[4];
#pragma unroll
  for (int g = 0; g < 4; ++g) {
    bv0[g] = bih0[g*HH + cmy] + bhh0[g*HH + cmy];
    bv1[g] = bih1[g*HH + cmy] + bhh1[g*HH + cmy];
  }

  float cst0 = 0.f, cst1 = 0.f;
  const int beff = (b15 < 8) ? b15 : 7;
  const int bsw  = beff << 1;      // conflict-free swizzle (r21: conflicts -> ~0)
  if (tid == 0) *dead = 0;
  __syncthreads();

  for (int st = 0; st <= TT; ++st) {
    const int tcur = (st < TT) ? st : (TT - 1);
    const __half* h0r = h0s + (size_t)(st & 1)*BB*HH;
    const __half* h1r = h1s + (size_t)(st & 1)*BB*HH;

    // ================= PHASE A =================
    if (wv == 0) fpoll(flgA, (unsigned)st, lane, dead);
    __syncthreads();

    // load x(st) + h0 (640 units; 3 iters)
    u32x4 stgA[3]; int phyA[3];
#pragma unroll
    for (int ii = 0; ii < 3; ++ii) {
      int idx = tid + NTHR*ii;
      phyA[ii] = -1;
      if (idx < 640) {
        const __half* src; int phys;
        if (idx < 128) { int b = idx>>4, u = idx&15;
          src = xh + (size_t)(bg8+b)*TT*DIN + (size_t)tcur*DIN + u*8;
          phys = b*16 + (u ^ ((b<<1)&15)); }
        else           { int i2 = idx-128, b = i2>>6, u = i2&63;
          src = h0r + (size_t)(bg8+b)*HH + u*8;
          phys = 128 + b*64 + (u ^ (b<<1)); }
        phyA[ii] = phys;
        stgA[ii] = ld16m(src);
      }
    }
    asm volatile("s_waitcnt vmcnt(0)" ::: "memory");   // loads + prev h1' store acks
    __builtin_amdgcn_sched_barrier(0);
    if (tid == 0)   // certify h1(st-2) (stored at end of step st-1, ack'd just now)
      __hip_atomic_store(flgB + r, (unsigned)st, __ATOMIC_RELAXED, __HIP_MEMORY_SCOPE_AGENT);
#pragma unroll
    for (int ii = 0; ii < 3; ++ii)
      if (phyA[ii] >= 0)
        *reinterpret_cast<u32x4*>(smbase + phyA[ii]*16) = stgA[ii];
    __syncthreads();

    // MFMA: L0 (20) + L1A (16, Wih1 x h0)
    f32x4 a0a = {0.f,0.f,0.f,0.f}, a0b = a0a, a1a = a0a, a1b = a0a;
#pragma unroll
    for (int m = 0; m < 20; ++m) {
      int phys = (m < 4) ? (beff*16 + ((4*m + kg) ^ (bsw & 15)))
                         : (128 + beff*64 + ((4*(m-4) + kg) ^ bsw));
      f16x8 bf = *reinterpret_cast<const f16x8*>(smbase + phys*16);
      if (m & 1) a0b = __builtin_amdgcn_mfma_f32_16x16x32_f16(af0[m], bf, a0b, 0, 0, 0);
      else       a0a = __builtin_amdgcn_mfma_f32_16x16x32_f16(af0[m], bf, a0a, 0, 0, 0);
    }
#pragma unroll
    for (int m = 0; m < 16; ++m) {
      int phys = 128 + beff*64 + ((4*m + kg) ^ bsw);
      f16x8 bf = *reinterpret_cast<const f16x8*>(smbase + phys*16);
      if (m & 1) a1b = __builtin_amdgcn_mfma_f32_16x16x32_f16(af1[m], bf, a1b, 0, 0, 0);
      else       a1a = __builtin_amdgcn_mfma_f32_16x16x32_f16(af1[m], bf, a1a, 0, 0, 0);
    }

    // gates L0 -> hout[0]
    if (st < TT) {
      f32x4 a0 = a0a + a0b;
      float gi = sigm (a0[0] + bv0[0]);
      float gf = sigm (a0[1] + bv0[1]);
      float gg = tanhf(a0[2] + bv0[2]);
      float go = sigm (a0[3] + bv0[3]);
      cst0 = gf*cst0 + gi*gg;
      float hn = go * tanhf(cst0);
      if (b15 < 8) hout[(0*8 + b15)*16 + 4*wv + kg] = __float2half(hn);
    }
    __syncthreads();

    // wave0: issue h0' stores (no wait); wave1: pollB concurrently
    if (tid < 32 && st < TT) {
      int b = tid >> 2, part = tid & 3;
      u64 v = *reinterpret_cast<u64*>(hout + (0*8 + b)*16 + part*4);
      __half* base = h0s + (size_t)((st + 1) & 1)*BB*HH;
      st8m(base + (size_t)(bg8+b)*HH + 16*r + part*4, v);
    }
    if (wv == 1) fpoll(flgB, (unsigned)st, lane, dead);
    __syncthreads();

    // ================= PHASE B =================
    // load h1 (512 units; 2 iters); vmcnt covers h0' store acks too
    u32x4 stgB[2];
#pragma unroll
    for (int ii = 0; ii < 2; ++ii) {
      int idx = tid + NTHR*ii;           // 0..511
      int b = idx >> 6, u = idx & 63;
      stgB[ii] = ld16m(h1r + (size_t)(bg8+b)*HH + u*8);
    }
    asm volatile("s_waitcnt vmcnt(0)" ::: "memory");
    __builtin_amdgcn_sched_barrier(0);
    if (tid == 0)   // certify h0(st) (stores ack'd by the vmcnt above)
      __hip_atomic_store(flgA + r, (unsigned)(st + 1), __ATOMIC_RELAXED, __HIP_MEMORY_SCOPE_AGENT);
#pragma unroll
    for (int ii = 0; ii < 2; ++ii) {
      int idx = tid + NTHR*ii;
      int b = idx >> 6, u = idx & 63;
      *reinterpret_cast<u32x4*>(smbase + (640 + b*64 + (u ^ (b<<1)))*16) = stgB[ii];
    }
    __syncthreads();

    // MFMA: L1B (16, Whh1 x h1)
#pragma unroll
    for (int m = 16; m < 32; ++m) {
      int phys = 640 + beff*64 + ((4*(m-16) + kg) ^ bsw);
      f16x8 bf = *reinterpret_cast<const f16x8*>(smbase + phys*16);
      if (m & 1) a1b = __builtin_amdgcn_mfma_f32_16x16x32_f16(af1[m], bf, a1b, 0, 0, 0);
      else       a1a = __builtin_amdgcn_mfma_f32_16x16x32_f16(af1[m], bf, a1a, 0, 0, 0);
    }

    // gates L1 -> hout[1]
    if (st >= 1) {
      f32x4 a1 = a1a + a1b;
      float gi = sigm (a1[0] + bv1[0]);
      float gf = sigm (a1[1] + bv1[1]);
      float gg = tanhf(a1[2] + bv1[2]);
      float go = sigm (a1[3] + bv1[3]);
      cst1 = gf*cst1 + gi*gg;
      float hn = go * tanhf(cst1);
      if (b15 < 8) hout[(1*8 + b15)*16 + 4*wv + kg] = __float2half(hn);
    }
    __syncthreads();

    // wave0: issue h1' stores (ack folded into next step's phase-A vmcnt)
    if (tid < 32 && st >= 1) {
      int b = tid >> 2, part = tid & 3;
      u64 v = *reinterpret_cast<u64*>(hout + (1*8 + b)*16 + part*4);
      __half* base = h1s + (size_t)((st + 1) & 1)*BB*HH;
      st8m(base + (size_t)(bg8+b)*HH + 16*r + part*4, v);
    }
  }

  // ---- epilogue: certify final h1(TT-1), then FC ----
  asm volatile("s_waitcnt vmcnt(0)" ::: "memory");
  if (tid == 0)
    __hip_atomic_store(flgB + r, (unsigned)(TT + 1), __ATOMIC_RELAXED, __HIP_MEMORY_SCOPE_AGENT);
  if (wv == 0) fpoll(flgB, (unsigned)(TT + 1), lane, dead);
  __syncthreads();
  {
    const __half* h1f = h1s + (size_t)BB*HH;   // parity (TT+1)&1 = 1
    int oi = tid >> 3, kp = tid & 7;
    int b  = oi >> 2, cc = oi & 3;
    int ocol = 4*r + cc;
    const u64* h8 = reinterpret_cast<const u64*>(h1f + (size_t)(bg8+b)*HH) + kp*16;
    const float* wrow = fcw + (size_t)ocol*HH + kp*64;
    float p = 0.f;
#pragma unroll
    for (int kk = 0; kk < 16; ++kk) {
      u64 v = ld8m(h8 + kk);
      __half2 hlo = __builtin_bit_cast(__half2, (unsigned)(v & 0xffffffffull));
      __half2 hhi = __builtin_bit_cast(__half2, (unsigned)(v >> 32));
      float2 flo = __half22float2(hlo), fhi = __half22float2(hhi);
      float4 w = *reinterpret_cast<const float4*>(wrow + kk*4);
      p += flo.x*w.x + flo.y*w.y + fhi.x*w.z + fhi.y*w.w;
    }
    p += __shfl_xor(p, 1);
    p += __shfl_xor(p, 2);
    p += __shfl_xor(p, 4);
    if (kp == 0) out[(size_t)(bg8+b)*128 + ocol] = p + fcb[ocol];
  }
}

__global__ void sentinel_fail(float* out, float v) { out[threadIdx.x] = v; }

extern "C" void kernel_launch(void* const* d_in, const int* in_sizes, int n_in,
                              void* d_out, int out_size, void* d_ws, size_t ws_size,
                              hipStream_t stream) {
  const float* x    = (const float*)d_in[0];
  const float* Wih0 = (const float*)d_in[1];
  const float* Whh0 = (const float*)d_in[2];
  const float* bih0 = (const float*)d_in[3];
  const float* bhh0 = (const float*)d_in[4];
  const float* Wih1 = (const float*)d_in[5];
  const float* Whh1 = (const float*)d_in[6];
  const float* bih1 = (const float*)d_in[7];
  const float* bhh1 = (const float*)d_in[8];
  const float* fcw  = (const float*)d_in[9];
  const float* fcb  = (const float*)d_in[10];
  float* out = (float*)d_out;
  float* ws  = (float*)d_ws;
  (void)in_sizes; (void)n_in; (void)out_size;

  const size_t need = 524288 + (size_t)BB*TT*DIN*2;
  if (ws_size < need) {
    sentinel_fail<<<1, 128, 0, stream>>>(out, 2.0e6f);
    return;
  }

  const int smem_bytes = 108*1024;   // 1 WG/CU (occupancy axis closed)
  hipFuncSetAttribute(reinterpret_cast<const void*>(&lstm2_sp),
                      hipFuncAttributeMaxDynamicSharedMemorySize, smem_bytes);
  hipFuncSetAttribute(reinterpret_cast<const void*>(&prep_flush),
                      hipFuncAttributeMaxDynamicSharedMemorySize, smem_bytes);

  (void)hipGetLastError();
  prep_flush<<<dim3(NWG), dim3(64), smem_bytes, stream>>>();
  xcvt<<<dim3(2048), dim3(NTHR), 0, stream>>>(
      x, reinterpret_cast<u64*>(reinterpret_cast<char*>(d_ws) + 524288));
  prep_zero<<<dim3(NWG), dim3(NTHR), 0, stream>>>((unsigned*)d_ws);
  lstm2_sp<<<dim3(NWG), dim3(NTHR), smem_bytes, stream>>>(
      Wih0, Whh0, bih0, bhh0, Wih1, Whh1, bih1, bhh1, fcw, fcb, out, ws);
  hipError_t e = hipGetLastError();
  if (e != hipSuccess) {
    sentinel_fail<<<1, 128, 0, stream>>>(out, 1.0e6f);
  }
}